// Round 13
// baseline (253.721 us; speedup 1.0000x reference)
//
#include <hip/hip_runtime.h>
#include <hip/hip_cooperative_groups.h>
#include <hip/hip_bf16.h>

#define NN 2048
#define FF 64
#define NH 8
#define BDIM 4
#define BH 32        // BDIM*NH

namespace cg = cooperative_groups;

typedef __attribute__((ext_vector_type(8))) short short8;
typedef __attribute__((ext_vector_type(4))) float floatx4;
typedef __attribute__((ext_vector_type(4))) unsigned uint4v;

__device__ __forceinline__ float LDIN(const void* p, size_t i, int b16) {
    return b16 ? __bfloat162float(((const __hip_bfloat16*)p)[i]) : ((const float*)p)[i];
}
__device__ __forceinline__ unsigned packhi(float f0, float f1) {
    return __builtin_amdgcn_perm(__float_as_uint(f1), __float_as_uint(f0), 0x07060302);
}
__device__ __forceinline__ float hitrunc(float x) {
    return __uint_as_float(__float_as_uint(x) & 0xFFFF0000u);
}
__device__ __forceinline__ ushort bf16bits(float v) {
    __hip_bfloat16 b = __float2bfloat16(v);
    return __builtin_bit_cast(ushort, b);
}
// XOR-swizzled LDS index (stride 64 shorts, 8-short groups). col must be 4-aligned.
__device__ __forceinline__ int SWZ(int row, int col) {
    return row * 64 + ((((col >> 3) ^ (row & 7)) << 3) | (col & 7));
}
__device__ __forceinline__ float fast_tanh(float v) {
    float ex = __expf(2.0f * v);
    return 1.0f - 2.0f * __builtin_amdgcn_rcpf(ex + 1.0f);
}
__device__ __forceinline__ int sniff_b16(const void* h) {
    unsigned word = ((const unsigned*)h)[threadIdx.x & 63];
    unsigned lowexp = (word >> 7) & 0xFFu;
    bool plaus = (lowexp >= 96u && lowexp <= 159u);
    unsigned long long m = __ballot(plaus);
    return (__popcll(m) >= 48) ? 1 : 0;
}

// =================== Fused cooperative kernel =================================
// grid 256 x 512 (1 block/CU). Phase A: proj, 4 tiles/block. grid.sync.
// Phase B: attn, 256 i-rows/block (bh = bid>>3, seg = bid&7).
__global__ __launch_bounds__(512, 2) void k_fused(
    const void* __restrict__ h, const void* __restrict__ w,
    const void* __restrict__ asrc, const void* __restrict__ adst,
    const void* __restrict__ bias, void* __restrict__ out,
    ushort* __restrict__ hpTt, float* __restrict__ rArr,
    float* __restrict__ edHa, float* __restrict__ edLa)
{
    __shared__ __align__(16) ushort SH[32768];   // 64 KB, phase-aliased
    __shared__ int sb16;
    // LDS layout (shorts): wHi @0, wLo @4096, aHi[ts] @8192+ts*4096,
    // aLo[ts] @16384+ts*4096, trans[ts] @24576+ts*4096. No pointer arrays
    // (addrspacecast static-init is rejected by gfx950 codegen).

    const int t = threadIdx.x;
    const int bid = blockIdx.x;
    const int lane = t & 63, wv = t >> 6;
    const int ml = lane & 15, q = lane >> 4;

    if (t < 64) {
        int f = sniff_b16(h);
        if (t == 0) sb16 = f;
    }
    __syncthreads();
    const int b16 = sb16;

    // ---------------- Phase A: projection ------------------------------------
    const int gt0 = bid * 4;                 // 4 tiles, same (b,hd)
    const int hd = (gt0 >> 5) & 7;
    const int b  = gt0 >> 8;
    const int bh = b * NH + hd;

    // stage w (transposed, split) once per block
    {
        const int n = t & 63, kq = (t >> 6) * 4;
        if (b16) {
            const ushort* wp = (const ushort*)w + (size_t)hd * FF * FF;
#pragma unroll
            for (int g = 0; g < 2; ++g) {
                int kb = g * 32 + kq;
                ushort v0 = wp[(kb + 0) * FF + n];
                ushort v1 = wp[(kb + 1) * FF + n];
                ushort v2 = wp[(kb + 2) * FF + n];
                ushort v3 = wp[(kb + 3) * FF + n];
                uint2 pk = { (unsigned)v0 | ((unsigned)v1 << 16),
                             (unsigned)v2 | ((unsigned)v3 << 16) };
                *(uint2*)&SH[SWZ(n, kb)] = pk;
            }
        } else {
            const float* wp = (const float*)w + (size_t)hd * FF * FF;
#pragma unroll
            for (int g = 0; g < 2; ++g) {
                int kb = g * 32 + kq;
                float x0 = wp[(kb + 0) * FF + n];
                float x1 = wp[(kb + 1) * FF + n];
                float x2 = wp[(kb + 2) * FF + n];
                float x3 = wp[(kb + 3) * FF + n];
                uint2 hi2 = { packhi(x0, x1), packhi(x2, x3) };
                uint2 lo2 = { packhi(x0 - hitrunc(x0), x1 - hitrunc(x1)),
                              packhi(x2 - hitrunc(x2), x3 - hitrunc(x3)) };
                *(uint2*)&SH[SWZ(n, kb)] = hi2;
                *(uint2*)&SH[4096 + SWZ(n, kb)] = lo2;
            }
        }
    }
    __syncthreads();

    // hoisted B-fragments (stable across tiles)
    short8 bhf[4][2], blf[4][2];
#pragma unroll
    for (int nt = 0; nt < 4; ++nt)
#pragma unroll
        for (int kc = 0; kc < 2; ++kc) {
            bhf[nt][kc] = *(const short8*)&SH[SWZ(nt * 16 + ml, kc * 32 + q * 8)];
            if (!b16) blf[nt][kc] = *(const short8*)&SH[4096 + SWZ(nt * 16 + ml, kc * 32 + q * 8)];
        }
    float aS[4], aD[4];
#pragma unroll
    for (int nt = 0; nt < 4; ++nt) {
        aS[nt] = LDIN(asrc, hd * FF + nt * 16 + ml, b16);
        aD[nt] = LDIN(adst, hd * FF + nt * 16 + ml, b16);
    }

    const int tp = wv >> 2, wl = wv & 3;     // wave's tile-pair slot / M-tile
    for (int it2 = 0; it2 < 2; ++it2) {
        // stage h for 2 tiles (thread t>>8 selects tile)
        {
            const int ts = t >> 8, local = t & 255;
            const int rt = (gt0 + it2 * 2 + ts) & 31;
            if (b16) {
                const ushort* hsrc = (const ushort*)h + (size_t)(b * NN + rt * 64) * FF;
#pragma unroll
                for (int g0 = 0; g0 < 2; ++g0) {
                    int g = local + g0 * 256;
                    int row = g >> 3, c8 = (g & 7) * 8;
                    uint4v u = *(const uint4v*)(hsrc + row * FF + c8);
                    *(uint4v*)&SH[8192 + ts * 4096 + SWZ(row, c8)] = u;
                }
            } else {
                const float* hsrc = (const float*)h + (size_t)(b * NN + rt * 64) * FF;
#pragma unroll
                for (int g0 = 0; g0 < 4; ++g0) {
                    int g = local + g0 * 256;
                    int row = g >> 4, c4 = (g & 15) * 4;
                    floatx4 x = *(const floatx4*)(hsrc + row * FF + c4);
                    uint2 hi2 = { packhi(x[0], x[1]), packhi(x[2], x[3]) };
                    uint2 lo2 = { packhi(x[0] - hitrunc(x[0]), x[1] - hitrunc(x[1])),
                                  packhi(x[2] - hitrunc(x[2]), x[3] - hitrunc(x[3])) };
                    *(uint2*)&SH[8192 + ts * 4096 + SWZ(row, c4)] = hi2;
                    *(uint2*)&SH[16384 + ts * 4096 + SWZ(row, c4)] = lo2;
                }
            }
        }
        __syncthreads();

        short8 ah[2], al[2];
#pragma unroll
        for (int kc = 0; kc < 2; ++kc) {
            ah[kc] = *(const short8*)&SH[8192 + tp * 4096 + SWZ(wl * 16 + ml, kc * 32 + q * 8)];
            if (!b16) al[kc] = *(const short8*)&SH[16384 + tp * 4096 + SWZ(wl * 16 + ml, kc * 32 + q * 8)];
        }
        floatx4 acc[4];
#pragma unroll
        for (int nt = 0; nt < 4; ++nt) {
            floatx4 a = {0.f, 0.f, 0.f, 0.f};
            if (b16) {
#pragma unroll
                for (int kc = 0; kc < 2; ++kc)
                    a = __builtin_amdgcn_mfma_f32_16x16x32_bf16(ah[kc], bhf[nt][kc], a, 0, 0, 0);
            } else {
#pragma unroll
                for (int kc = 0; kc < 2; ++kc) {
                    a = __builtin_amdgcn_mfma_f32_16x16x32_bf16(ah[kc], bhf[nt][kc], a, 0, 0, 0);
                    a = __builtin_amdgcn_mfma_f32_16x16x32_bf16(ah[kc], blf[nt][kc], a, 0, 0, 0);
                    a = __builtin_amdgcn_mfma_f32_16x16x32_bf16(al[kc], bhf[nt][kc], a, 0, 0, 0);
                }
            }
            acc[nt] = a;
        }
#pragma unroll
        for (int nt = 0; nt < 4; ++nt) {
            ushort b0 = bf16bits(acc[nt][0]), b1 = bf16bits(acc[nt][1]);
            ushort b2 = bf16bits(acc[nt][2]), b3 = bf16bits(acc[nt][3]);
            uint2 pk = { (unsigned)b0 | ((unsigned)b1 << 16),
                         (unsigned)b2 | ((unsigned)b3 << 16) };
            *(uint2*)&SH[24576 + tp * 4096 + SWZ(nt * 16 + ml, wl * 16 + q * 4)] = pk;
        }
        float ps[4] = {0.f, 0.f, 0.f, 0.f}, pd[4] = {0.f, 0.f, 0.f, 0.f};
#pragma unroll
        for (int nt = 0; nt < 4; ++nt)
#pragma unroll
            for (int reg = 0; reg < 4; ++reg) {
                float tv = fast_tanh(acc[nt][reg]);
                ps[reg] += tv * aS[nt];
                pd[reg] += tv * aD[nt];
            }
#pragma unroll
        for (int msk = 1; msk < 16; msk <<= 1)
#pragma unroll
            for (int reg = 0; reg < 4; ++reg) {
                ps[reg] += __shfl_xor(ps[reg], msk, 64);
                pd[reg] += __shfl_xor(pd[reg], msk, 64);
            }
        if (ml == 0) {
            const int rt = (gt0 + it2 * 2 + tp) & 31;
#pragma unroll
            for (int reg = 0; reg < 4; ++reg) {
                int i = bh * NN + rt * 64 + wl * 16 + q * 4 + reg;
                float sv = ps[reg], dv = pd[reg];
                rArr[i] = __expf(-0.8f * sv);
                edHa[i] = __expf(dv);
                edLa[i] = __expf(0.2f * dv);
            }
        }
        __syncthreads();
        {   // coalesced tiled store of both tiles
            const int ts = t >> 8, local = t & 255;
            const int rt = (gt0 + it2 * 2 + ts) & 31;
            const int o = local >> 2, part = (local & 3) * 16;
            uint4v v0 = *(const uint4v*)&SH[24576 + ts * 4096 + SWZ(o, part)];
            uint4v v1 = *(const uint4v*)&SH[24576 + ts * 4096 + SWZ(o, part + 8)];
            ushort* dst = hpTt + (((size_t)bh * 32 + rt) * 64 + o) * 64 + part;
            *(uint4v*)dst = v0;
            *(uint4v*)(dst + 8) = v1;
        }
        __syncthreads();
    }

    __threadfence();
    cg::this_grid().sync();
    __threadfence();

    // ---------------- Phase B: attention -------------------------------------
    // LDS layout (shorts): Bc[buf] @buf*4096 (16 KB), ehS @8192 (floats), elS @12288.
    const int bh2 = bid >> 3;
    const int seg = bid & 7;
    const ushort* src = hpTt + (size_t)bh2 * NN * FF;

    ((floatx4*)(SH + 8192))[t]  = ((const floatx4*)(edHa + bh2 * NN))[t];
    ((floatx4*)(SH + 16384))[t] = ((const floatx4*)(edLa + bh2 * NN))[t];

    float r2[2];
#pragma unroll
    for (int g2 = 0; g2 < 2; ++g2)
        r2[g2] = rArr[bh2 * NN + seg * 256 + g2 * 128 + wv * 16 + ml];

    const short8 ONESB = {0x3F80, 0x3F80, 0x3F80, 0x3F80,
                          0x3F80, 0x3F80, 0x3F80, 0x3F80};

    floatx4 acc2[2][4];
#pragma unroll
    for (int g2 = 0; g2 < 2; ++g2)
#pragma unroll
        for (int nt = 0; nt < 4; ++nt) acc2[g2][nt] = (floatx4){0.f, 0.f, 0.f, 0.f};
    floatx4 accD0 = {0.f, 0.f, 0.f, 0.f};
    floatx4 accD1 = {0.f, 0.f, 0.f, 0.f};

    auto stage = [&](int c) {
        uint4v u = *(const uint4v*)(src + (size_t)c * 4096 + t * 8);
        *(uint4v*)&SH[(c & 1) * 4096 + SWZ(t >> 3, (t & 7) * 8)] = u;
    };
    auto compute = [&](int c) {
        const int j0 = c * 64, bufo = (c & 1) * 4096;
        const float* ehS = (const float*)(SH + 8192);
        const float* elS = (const float*)(SH + 16384);
#pragma unroll
        for (int ks = 0; ks < 2; ++ks) {
            const int col = ks * 32 + q * 8;
            floatx4 eh0 = *(const floatx4*)&ehS[j0 + col];
            floatx4 eh1 = *(const floatx4*)&ehS[j0 + col + 4];
            floatx4 el0 = *(const floatx4*)&elS[j0 + col];
            floatx4 el1 = *(const floatx4*)&elS[j0 + col + 4];
            short8 Bf[4];
#pragma unroll
            for (int nt = 0; nt < 4; ++nt)
                Bf[nt] = *(const short8*)&SH[bufo + SWZ(nt * 16 + ml, col)];
#pragma unroll
            for (int g2 = 0; g2 < 2; ++g2) {
                float p[8];
#pragma unroll
                for (int j = 0; j < 4; ++j) {
                    p[j]     = fmaxf(eh0[j], r2[g2] * el0[j]);
                    p[j + 4] = fmaxf(eh1[j], r2[g2] * el1[j]);
                }
                uint4v hv = { packhi(p[0], p[1]), packhi(p[2], p[3]),
                              packhi(p[4], p[5]), packhi(p[6], p[7]) };
                short8 PH = __builtin_bit_cast(short8, hv);
#pragma unroll
                for (int nt = 0; nt < 4; ++nt)
                    acc2[g2][nt] = __builtin_amdgcn_mfma_f32_16x16x32_bf16(PH, Bf[nt], acc2[g2][nt], 0, 0, 0);
                if (g2 == 0) accD0 = __builtin_amdgcn_mfma_f32_16x16x32_bf16(PH, ONESB, accD0, 0, 0, 0);
                else         accD1 = __builtin_amdgcn_mfma_f32_16x16x32_bf16(PH, ONESB, accD1, 0, 0, 0);
            }
        }
    };

    stage(0);
    __syncthreads();
    for (int c = 0; c < 32; ++c) {
        if (c + 1 < 32) stage(c + 1);
        compute(c);
        __syncthreads();
    }

    float biasv[4];
#pragma unroll
    for (int nt = 0; nt < 4; ++nt) biasv[nt] = LDIN(bias, nt * 16 + ml, b16);

#pragma unroll
    for (int g2 = 0; g2 < 2; ++g2) {
        const int i0 = seg * 256 + g2 * 128 + wv * 16;
#pragma unroll
        for (int reg = 0; reg < 4; ++reg) {
            float dv = g2 ? accD1[reg] : accD0[reg];
            float inv = 1.0f / dv;
            int i = i0 + q * 4 + reg;
#pragma unroll
            for (int nt = 0; nt < 4; ++nt) {
                float val = acc2[g2][nt][reg] * inv + biasv[nt];
                size_t oi = ((size_t)bh2 * NN + i) * FF + nt * 16 + ml;
                if (b16) ((__hip_bfloat16*)out)[oi] = __float2bfloat16(val);
                else     ((float*)out)[oi] = val;
            }
        }
    }
}

// =================== Fallback path (round-11 kernels) =========================
__global__ __launch_bounds__(256) void k_prep(
    const void* __restrict__ h, const void* __restrict__ w,
    ushort* __restrict__ wF, int* __restrict__ flagOut)
{
    const int hd = blockIdx.x, t = threadIdx.x;
    __shared__ int sb16;
    if (t < 64) {
        int f = sniff_b16(h);
        if (t == 0) { sb16 = f; if (hd == 0) flagOut[0] = f; }
    }
    __syncthreads();
    const int b16 = sb16;
#pragma unroll
    for (int g = 0; g < 2; ++g) {
        int gi = t * 2 + g;
        int ml = gi & 15, q = (gi >> 4) & 3, kc = (gi >> 6) & 1, nt = (gi >> 7) & 3;
        int n = nt * 16 + ml, kb = kc * 32 + q * 8;
        size_t off = (size_t)hd * 4096 + ((nt * 2 + kc) * 4 + q) * 128 + ml * 8;
        if (b16) {
            const ushort* wp = (const ushort*)w + (size_t)hd * FF * FF;
            ushort hi[8];
#pragma unroll
            for (int j = 0; j < 8; ++j) hi[j] = wp[(kb + j) * FF + n];
            *(uint4v*)&wF[off] = __builtin_bit_cast(uint4v, *(short8*)hi);
            short8 z = {0, 0, 0, 0, 0, 0, 0, 0};
            *(uint4v*)&wF[off + 32768] = __builtin_bit_cast(uint4v, z);
        } else {
            const float* wp = (const float*)w + (size_t)hd * FF * FF;
            float x[8];
#pragma unroll
            for (int j = 0; j < 8; ++j) x[j] = wp[(kb + j) * FF + n];
            uint4v hv = { packhi(x[0], x[1]), packhi(x[2], x[3]),
                          packhi(x[4], x[5]), packhi(x[6], x[7]) };
            uint4v lv = { packhi(x[0] - hitrunc(x[0]), x[1] - hitrunc(x[1])),
                          packhi(x[2] - hitrunc(x[2]), x[3] - hitrunc(x[3])),
                          packhi(x[4] - hitrunc(x[4]), x[5] - hitrunc(x[5])),
                          packhi(x[6] - hitrunc(x[6]), x[7] - hitrunc(x[7])) };
            *(uint4v*)&wF[off] = hv;
            *(uint4v*)&wF[off + 32768] = lv;
        }
    }
}

__global__ __launch_bounds__(256) void k_proj(
    const void* __restrict__ h, const ushort* __restrict__ wF,
    const void* __restrict__ asrc, const void* __restrict__ adst,
    ushort* __restrict__ hpTt, float* __restrict__ rArr,
    float* __restrict__ edHa, float* __restrict__ edLa)
{
    const int t  = threadIdx.x;
    const int rt = blockIdx.x & 31;
    const int hd = (blockIdx.x >> 5) & 7;
    const int b  = blockIdx.x >> 8;
    const int bh = b * NH + hd;
    const int r0 = rt * 64;

    __shared__ int sb16;
    __shared__ ushort aHi[64 * 64];
    __shared__ ushort aLo[64 * 64];
    __shared__ ushort trans[64 * 64];
    if (t < 64) {
        int f = sniff_b16(h);
        if (t == 0) sb16 = f;
    }
    __syncthreads();
    const int b16 = sb16;
    const int lane = t & 63, wv = t >> 6;
    const int ml = lane & 15, q = lane >> 4;

    if (b16) {
        const ushort* hsrc = (const ushort*)h + (size_t)(b * NN + r0) * FF;
#pragma unroll
        for (int g0 = 0; g0 < 2; ++g0) {
            int g = t + g0 * 256;
            int row = g >> 3, c8 = (g & 7) * 8;
            uint4v u = *(const uint4v*)(hsrc + row * FF + c8);
            *(uint4v*)&aHi[SWZ(row, c8)] = u;
        }
    } else {
        const float* hsrc = (const float*)h + (size_t)(b * NN + r0) * FF;
#pragma unroll
        for (int g0 = 0; g0 < 4; ++g0) {
            int g = t + g0 * 256;
            int row = g >> 4, c4 = (g & 15) * 4;
            floatx4 x = *(const floatx4*)(hsrc + row * FF + c4);
            uint2 hi2 = { packhi(x[0], x[1]), packhi(x[2], x[3]) };
            uint2 lo2 = { packhi(x[0] - hitrunc(x[0]), x[1] - hitrunc(x[1])),
                          packhi(x[2] - hitrunc(x[2]), x[3] - hitrunc(x[3])) };
            *(uint2*)&aHi[SWZ(row, c4)] = hi2;
            *(uint2*)&aLo[SWZ(row, c4)] = lo2;
        }
    }
    __syncthreads();

    short8 ah[2], al[2];
#pragma unroll
    for (int kc = 0; kc < 2; ++kc) {
        ah[kc] = *(const short8*)&aHi[SWZ(wv * 16 + ml, kc * 32 + q * 8)];
        if (!b16) al[kc] = *(const short8*)&aLo[SWZ(wv * 16 + ml, kc * 32 + q * 8)];
    }
    short8 bhf[4][2], blf[4][2];
    const ushort* wfh = wF + (size_t)hd * 4096;
#pragma unroll
    for (int nt = 0; nt < 4; ++nt)
#pragma unroll
        for (int kc = 0; kc < 2; ++kc) {
            size_t off = ((nt * 2 + kc) * 4 + q) * 128 + ml * 8;
            bhf[nt][kc] = __builtin_bit_cast(short8, *(const uint4v*)&wfh[off]);
            if (!b16) blf[nt][kc] = __builtin_bit_cast(short8, *(const uint4v*)&wfh[off + 32768]);
        }
    float aS[4], aD[4];
#pragma unroll
    for (int nt = 0; nt < 4; ++nt) {
        aS[nt] = LDIN(asrc, hd * FF + nt * 16 + ml, b16);
        aD[nt] = LDIN(adst, hd * FF + nt * 16 + ml, b16);
    }
    floatx4 acc[4];
#pragma unroll
    for (int nt = 0; nt < 4; ++nt) {
        floatx4 a = {0.f, 0.f, 0.f, 0.f};
        if (b16) {
#pragma unroll
            for (int kc = 0; kc < 2; ++kc)
                a = __builtin_amdgcn_mfma_f32_16x16x32_bf16(ah[kc], bhf[nt][kc], a, 0, 0, 0);
        } else {
#pragma unroll
            for (int kc = 0; kc < 2; ++kc) {
                a = __builtin_amdgcn_mfma_f32_16x16x32_bf16(ah[kc], bhf[nt][kc], a, 0, 0, 0);
                a = __builtin_amdgcn_mfma_f32_16x16x32_bf16(ah[kc], blf[nt][kc], a, 0, 0, 0);
                a = __builtin_amdgcn_mfma_f32_16x16x32_bf16(al[kc], bhf[nt][kc], a, 0, 0, 0);
            }
        }
        acc[nt] = a;
    }
#pragma unroll
    for (int nt = 0; nt < 4; ++nt) {
        ushort b0 = bf16bits(acc[nt][0]), b1 = bf16bits(acc[nt][1]);
        ushort b2 = bf16bits(acc[nt][2]), b3 = bf16bits(acc[nt][3]);
        uint2 pk = { (unsigned)b0 | ((unsigned)b1 << 16),
                     (unsigned)b2 | ((unsigned)b3 << 16) };
        *(uint2*)&trans[SWZ(nt * 16 + ml, wv * 16 + q * 4)] = pk;
    }
    float ps[4] = {0.f, 0.f, 0.f, 0.f}, pd[4] = {0.f, 0.f, 0.f, 0.f};
#pragma unroll
    for (int nt = 0; nt < 4; ++nt)
#pragma unroll
        for (int reg = 0; reg < 4; ++reg) {
            float tv = fast_tanh(acc[nt][reg]);
            ps[reg] += tv * aS[nt];
            pd[reg] += tv * aD[nt];
        }
#pragma unroll
    for (int msk = 1; msk < 16; msk <<= 1)
#pragma unroll
        for (int reg = 0; reg < 4; ++reg) {
            ps[reg] += __shfl_xor(ps[reg], msk, 64);
            pd[reg] += __shfl_xor(pd[reg], msk, 64);
        }
    if (ml == 0) {
#pragma unroll
        for (int reg = 0; reg < 4; ++reg) {
            int i = bh * NN + r0 + wv * 16 + q * 4 + reg;
            float sv = ps[reg], dv = pd[reg];
            rArr[i] = __expf(-0.8f * sv);
            edHa[i] = __expf(dv);
            edLa[i] = __expf(0.2f * dv);
        }
    }
    __syncthreads();
    {
        const int o = t >> 2, part = (t & 3) * 16;
        uint4v v0 = *(const uint4v*)&trans[SWZ(o, part)];
        uint4v v1 = *(const uint4v*)&trans[SWZ(o, part + 8)];
        ushort* dst = hpTt + (((size_t)bh * 32 + rt) * 64 + o) * 64 + part;
        *(uint4v*)dst = v0;
        *(uint4v*)(dst + 8) = v1;
    }
}

__global__ __launch_bounds__(512) void k_attn(
    const ushort* __restrict__ hpTt, const float* __restrict__ rArr,
    const float* __restrict__ edHa, const float* __restrict__ edLa,
    const void* __restrict__ bias, const int* __restrict__ flag,
    void* __restrict__ out)
{
    const int b16 = flag[0];
    const int t = threadIdx.x;
    const int wv = t >> 6, lane = t & 63;
    const int ml = lane & 15, q = lane >> 4;
    const int bh = blockIdx.x & 31;
    const int i0 = (blockIdx.x >> 5) * 128 + wv * 16;

    __shared__ ushort Bc0[64 * 64];
    __shared__ ushort Bc1[64 * 64];
    __shared__ __align__(16) float ehS[NN];
    __shared__ __align__(16) float elS[NN];

    ((floatx4*)ehS)[t] = ((const floatx4*)(edHa + bh * NN))[t];
    ((floatx4*)elS)[t] = ((const floatx4*)(edLa + bh * NN))[t];

    const ushort* src = hpTt + (size_t)bh * NN * FF;
    const float r = rArr[bh * NN + i0 + ml];
    const short8 ONESB = {0x3F80, 0x3F80, 0x3F80, 0x3F80,
                          0x3F80, 0x3F80, 0x3F80, 0x3F80};
    floatx4 acc[4];
#pragma unroll
    for (int nt = 0; nt < 4; ++nt) acc[nt] = (floatx4){0.f, 0.f, 0.f, 0.f};
    floatx4 accD = {0.f, 0.f, 0.f, 0.f};

    auto stage = [&](int c) {
        uint4v u = *(const uint4v*)(src + (size_t)c * 4096 + t * 8);
        ushort* d = (c & 1) ? Bc1 : Bc0;
        *(uint4v*)&d[SWZ(t >> 3, (t & 7) * 8)] = u;
    };
    auto compute = [&](int c) {
        const int j0 = c * 64;
        const ushort* buf = (c & 1) ? Bc1 : Bc0;
#pragma unroll
        for (int ks = 0; ks < 2; ++ks) {
            const int col = ks * 32 + q * 8;
            floatx4 eh0 = *(const floatx4*)&ehS[j0 + col];
            floatx4 eh1 = *(const floatx4*)&ehS[j0 + col + 4];
            floatx4 el0 = *(const floatx4*)&elS[j0 + col];
            floatx4 el1 = *(const floatx4*)&elS[j0 + col + 4];
            short8 Bf[4];
#pragma unroll
            for (int nt = 0; nt < 4; ++nt)
                Bf[nt] = *(const short8*)&buf[SWZ(nt * 16 + ml, col)];
            float p[8];
#pragma unroll
            for (int j = 0; j < 4; ++j) {
                p[j]     = fmaxf(eh0[j], r * el0[j]);
                p[j + 4] = fmaxf(eh1[j], r * el1[j]);
            }
            uint4v hv = { packhi(p[0], p[1]), packhi(p[2], p[3]),
                          packhi(p[4], p[5]), packhi(p[6], p[7]) };
            short8 PH = __builtin_bit_cast(short8, hv);
#pragma unroll
            for (int nt = 0; nt < 4; ++nt)
                acc[nt] = __builtin_amdgcn_mfma_f32_16x16x32_bf16(PH, Bf[nt], acc[nt], 0, 0, 0);
            accD = __builtin_amdgcn_mfma_f32_16x16x32_bf16(PH, ONESB, accD, 0, 0, 0);
        }
    };

    stage(0);
    __syncthreads();
    for (int c = 0; c < 32; ++c) {
        if (c + 1 < 32) stage(c + 1);
        compute(c);
        __syncthreads();
    }

    float biasv[4];
#pragma unroll
    for (int nt = 0; nt < 4; ++nt) biasv[nt] = LDIN(bias, nt * 16 + ml, b16);
#pragma unroll
    for (int reg = 0; reg < 4; ++reg) {
        float inv = 1.0f / accD[reg];
        int i = i0 + q * 4 + reg;
#pragma unroll
        for (int nt = 0; nt < 4; ++nt) {
            float val = acc[nt][reg] * inv + biasv[nt];
            size_t oi = ((size_t)bh * NN + i) * FF + nt * 16 + ml;
            if (b16) ((__hip_bfloat16*)out)[oi] = __float2bfloat16(val);
            else     ((float*)out)[oi] = val;
        }
    }
}

extern "C" void kernel_launch(void* const* d_in, const int* in_sizes, int n_in,
                              void* d_out, int out_size, void* d_ws, size_t ws_size,
                              hipStream_t stream) {
    const void* h    = d_in[0];
    // d_in[1] = adj (bool) — unused by reference
    const void* w    = d_in[2];
    const void* asrc = d_in[3];
    const void* adst = d_in[4];
    const void* bias = d_in[5];
    void* out = d_out;

    float* ws = (float*)d_ws;
    int*    flag = (int*)ws;                            // 16 ints
    ushort* hpTt = (ushort*)(ws + 16);                  // BH*NN*FF bf16, tiled
    float*  rArr = (float*)(hpTt + (size_t)BH * NN * FF);
    float*  edHa = rArr + BH * NN;
    float*  edLa = edHa + BH * NN;
    ushort* wF   = (ushort*)(edLa + BH * NN);           // 65536 shorts (hi|lo)

    void* args[] = { (void*)&h, (void*)&w, (void*)&asrc, (void*)&adst,
                     (void*)&bias, (void*)&out,
                     (void*)&hpTt, (void*)&rArr, (void*)&edHa, (void*)&edLa };
    hipError_t err = hipLaunchCooperativeKernel(
        reinterpret_cast<void*>(k_fused), dim3(256), dim3(512), args, 0, stream);
    if (err != hipSuccess) {
        (void)hipGetLastError();   // clear, take the 3-kernel fallback
        k_prep<<<NH, 256, 0, stream>>>(h, w, wF, flag);
        k_proj<<<BDIM * NH * 32, 256, 0, stream>>>(h, wF, asrc, adst,
                                                   hpTt, rArr, edHa, edLa);
        k_attn<<<BH * 16, 512, 0, stream>>>(hpTt, rArr, edHa, edLa,
                                            bias, flag, d_out);
    }
}